// Round 11
// baseline (99.725 us; speedup 1.0000x reference)
//
#include <hip/hip_runtime.h>
#include <hip/hip_bf16.h>

// FastGRNN 2-layer (SRNN2). T=2048, B=256, D=32, H0=H1=64, O=35, brick=32.
// Round 11: occupancy fix — 2 waves/SIMD everywhere.
// l0 "duo": 1024 blocks x 128 thr (2 waves). Wave w owns units [32w,32w+32):
//   per step 6 bf16 K=32 MFMA + 8 act/lane; h via XOR-swizzled bf16 LDS,
//   ONE lgkm-only barrier/step (global x prefetch stays in flight).
//   2048 waves = 2/SIMD -> cross-wave latency hiding.
// l1: round-10 transposed f16 K=16 math (proven), but 8 blocks x 512 thr with
//   2 independent batch-tiles per block -> 2 waves/SIMD on 8 CUs. x-part reads
//   f16 rows last0[t][batch][64] (direct B-frag k-slices, zero conversion).

#define NB    64
#define BS    32
#define BATCH 256
#define D0    32
#define H     64
#define OUTD  35
#define LOG2E 1.44269504088896340736f

typedef short    bf8   __attribute__((ext_vector_type(8)));
typedef _Float16 h4    __attribute__((ext_vector_type(4)));
typedef __fp16   hf2   __attribute__((ext_vector_type(2)));
typedef float    f32x4 __attribute__((ext_vector_type(4)));

union HB { h4 v; hf2 h[2]; unsigned u[2]; };
union U4BF8 { unsigned u[4]; bf8 v; };

__device__ __forceinline__ float rcp_fast(float x) {
    return __builtin_amdgcn_rcpf(x);
}
__device__ __forceinline__ float sigm(float x) {
    return rcp_fast(1.0f + __expf(-x));
}
__device__ __forceinline__ float tanh_fast(float x) {
    float q = rcp_fast(1.0f + __expf(-2.0f * x));
    return fmaf(2.0f, q, -1.0f);
}
__device__ __forceinline__ short f2bf(float f) {
    __hip_bfloat16 b = __float2bfloat16(f);
    return __builtin_bit_cast(short, b);
}
// packed pair -> v_cvt_pk_bf16_f32 (lo in bits[15:0])
__device__ __forceinline__ unsigned pk2bf(float lo, float hi) {
    __hip_bfloat162 h2 = __float22bfloat162_rn(make_float2(lo, hi));
    unsigned r;
    __builtin_memcpy(&r, &h2, 4);
    return r;
}
// packed pair -> f16 (v_cvt_pkrtz_f16_f32)
__device__ __forceinline__ unsigned pk2f16(float lo, float hi) {
    hf2 h2 = __builtin_amdgcn_cvt_pkrtz(lo, hi);
    unsigned r;
    __builtin_memcpy(&r, &h2, 4);
    return r;
}
// LDS-only barrier: drains ds ops, leaves global loads in flight
__device__ __forceinline__ void lds_barrier() {
    asm volatile("s_waitcnt lgkmcnt(0)\n\ts_barrier" ::: "memory");
}
// byte swizzle within a 128-B h row (16-aligned: b128 reads stay aligned)
__device__ __forceinline__ int swz_x(int s) {
    return ((s & 7) << 4) ^ ((s & 8) << 2);
}
// 2-transcendental fused activation (round-10 proven)
__device__ __forceinline__ void act_update(float pre, float bgp, float Ku,
                                           float zs, float zns, float& hcr) {
    float t  = fminf(fmaxf(pre, -12.f), 12.f);
    float a  = exp2f(fmaf(t, -LOG2E, bgp));
    float b  = a * a * Ku;
    float da = 1.f + a, db = 1.f + b;
    float rr = rcp_fast(da * db);
    float z  = rr * db;
    float ib = rr * da;
    float c  = fmaf(2.f, ib, -1.f);
    float w  = fmaf(-zs, z, zns);
    hcr = fmaf(z, hcr, w * c);
}

// --------- Layer 0 duo: 1024 blocks x 128 thr; wave w owns 32 units ---------
__global__ __launch_bounds__(128, 2) void l0_kernel(
    const float* __restrict__ x,      // [2048][256][32]
    const float* __restrict__ W,      // [32][64]
    const float* __restrict__ U,      // [64][64]
    const float* __restrict__ bg,
    const float* __restrict__ bu,
    const float* __restrict__ zeta,
    const float* __restrict__ nu,
    unsigned short* __restrict__ last0)  // f16 [64][256][64]
{
    __shared__ unsigned char hb[2][16 * 128];   // bf16 h, swizzled rows

    const int tid  = threadIdx.x;
    const int lane = tid & 63;
    const int w    = __builtin_amdgcn_readfirstlane(tid >> 6);   // 0..1
    const int l15  = lane & 15;
    const int lg   = lane >> 4;

    const int brick     = blockIdx.x >> 4;
    const int batchbase = (blockIdx.x & 15) << 4;

    // zero hb[0]: 2 KB / 128 thr = 16 B each
    *reinterpret_cast<float4*>(&hb[0][tid * 16]) = make_float4(0.f, 0.f, 0.f, 0.f);

    // weight B-frags (normal orientation): col = uc, k = 8lg+j
    bf8 Wb[2], Ub0[2], Ub1[2];
    float bgc[2], buc[2];
#pragma unroll
    for (int T = 0; T < 2; ++T) {
        const int uc = 32 * w + 16 * T + l15;
#pragma unroll
        for (int j = 0; j < 8; ++j) {
            Wb[T][j]  = f2bf(W[(8 * lg + j) * H + uc]);
            Ub0[T][j] = f2bf(U[(8 * lg + j) * H + uc]);
            Ub1[T][j] = f2bf(U[(32 + 8 * lg + j) * H + uc]);
        }
        bgc[T] = bg[uc];
        buc[T] = bu[uc];
    }

    const float zs  = sigm(zeta[0]);
    const float ns  = sigm(nu[0]);
    const float zns = zs + ns;

    float hc[2][4];
#pragma unroll
    for (int T = 0; T < 2; ++T)
#pragma unroll
        for (int r = 0; r < 4; ++r) hc[T][r] = 0.f;

    const float* xbase = x + ((size_t)(brick * BS) * BATCH + batchbase + l15) * D0 + 8 * lg;
    const size_t xstep = (size_t)BATCH * D0;

    float4 xa0 = reinterpret_cast<const float4*>(xbase)[0];
    float4 xa1 = reinterpret_cast<const float4*>(xbase)[1];
    float4 xn0 = reinterpret_cast<const float4*>(xbase + xstep)[0];
    float4 xn1 = reinterpret_cast<const float4*>(xbase + xstep)[1];

    // write byte offsets (loop-invariant): s = 4lg+r, unit col = 32w+16T+l15
    int woff[2][4];
#pragma unroll
    for (int T = 0; T < 2; ++T)
#pragma unroll
        for (int r = 0; r < 4; ++r) {
            int s = 4 * lg + r;
            woff[T][r] = s * 128 + (((32 * w + 16 * T + l15) * 2) ^ swz_x(s));
        }
    const int rswz = swz_x(l15);

    __syncthreads();

    int cur = 0;
#pragma unroll 1
    for (int t = 0; t < BS; ++t) {
        const int tp = (t + 2 < BS) ? (t + 2) : (BS - 1);
        float4 p0 = reinterpret_cast<const float4*>(xbase + (size_t)tp * xstep)[0];
        float4 p1 = reinterpret_cast<const float4*>(xbase + (size_t)tp * xstep)[1];

        U4BF8 xp;
        xp.u[0] = pk2bf(xa0.x, xa0.y);
        xp.u[1] = pk2bf(xa0.z, xa0.w);
        xp.u[2] = pk2bf(xa1.x, xa1.y);
        xp.u[3] = pk2bf(xa1.z, xa1.w);

        // h A-frags (row l15), swizzled conflict-free b128
        const unsigned char* hr = &hb[cur][l15 * 128];
        bf8 ha0 = *reinterpret_cast<const bf8*>(hr + ((16 * lg) ^ rswz));
        bf8 ha1 = *reinterpret_cast<const bf8*>(hr + ((64 + 16 * lg) ^ rswz));

        unsigned char* wb = &hb[cur ^ 1][0];
#pragma unroll
        for (int T = 0; T < 2; ++T) {
            f32x4 a = {0.f, 0.f, 0.f, 0.f};
            a = __builtin_amdgcn_mfma_f32_16x16x32_bf16(xp.v, Wb[T], a, 0, 0, 0);
            a = __builtin_amdgcn_mfma_f32_16x16x32_bf16(ha0, Ub0[T], a, 0, 0, 0);
            a = __builtin_amdgcn_mfma_f32_16x16x32_bf16(ha1, Ub1[T], a, 0, 0, 0);

#pragma unroll
            for (int r = 0; r < 4; ++r) {
                float z = sigm(a[r] + bgc[T]);
                float c = tanh_fast(a[r] + buc[T]);
                float wq = fmaf(-zs, z, zns);
                hc[T][r] = fmaf(z, hc[T][r], wq * c);
            }
            unsigned pkA = pk2bf(hc[T][0], hc[T][1]);
            unsigned pkB = pk2bf(hc[T][2], hc[T][3]);
            *reinterpret_cast<unsigned short*>(wb + woff[T][0]) = (unsigned short)pkA;
            *reinterpret_cast<unsigned short*>(wb + woff[T][1]) = (unsigned short)(pkA >> 16);
            *reinterpret_cast<unsigned short*>(wb + woff[T][2]) = (unsigned short)pkB;
            *reinterpret_cast<unsigned short*>(wb + woff[T][3]) = (unsigned short)(pkB >> 16);
        }
        lds_barrier();     // ds drained; x prefetch stays in flight
        cur ^= 1;
        xa0 = xn0; xa1 = xn1;
        xn0 = p0;  xn1 = p1;
    }

    // store last hidden state as f16 rows [brick*256 + batch][unit]
#pragma unroll
    for (int T = 0; T < 2; ++T) {
        unsigned pkA = pk2f16(hc[T][0], hc[T][1]);
        unsigned pkB = pk2f16(hc[T][2], hc[T][3]);
        const int uc = 32 * w + 16 * T + l15;
        unsigned short* op = last0 + ((size_t)(brick * BATCH + batchbase)) * H + uc;
        op[(size_t)(4 * lg + 0) * H] = (unsigned short)pkA;
        op[(size_t)(4 * lg + 1) * H] = (unsigned short)(pkA >> 16);
        op[(size_t)(4 * lg + 2) * H] = (unsigned short)pkB;
        op[(size_t)(4 * lg + 3) * H] = (unsigned short)(pkB >> 16);
    }
}

// ----- Layer 1: round-10 transposed f16 math; 8 blocks x 512 (2 tiles) ------
__global__ __launch_bounds__(512, 2) void l1_kernel(
    const unsigned short* __restrict__ last0,  // f16 [64][256][64]
    const float* __restrict__ W,               // [64][64]
    const float* __restrict__ U,               // [64][64]
    const float* __restrict__ bg,
    const float* __restrict__ bu,
    const float* __restrict__ zeta,
    const float* __restrict__ nu,
    const float* __restrict__ Wout,            // [64][35]
    const float* __restrict__ Bout,            // [35]
    float* __restrict__ out)                   // [256][35]
{
    __shared__ unsigned hx[2][2][4][4][16][2];  // [buf][pair][chunk][lg][s][dw] 8KB
    __shared__ float hsf[2][16][H];             // 8KB

    const int tid  = threadIdx.x;
    const int lane = tid & 63;
    const int pair = __builtin_amdgcn_readfirstlane(tid >> 8);       // 0..1
    const int T    = __builtin_amdgcn_readfirstlane((tid >> 6) & 3); // unit tile
    const int l15  = lane & 15;
    const int lg   = lane >> 4;

    const int batchbase = (blockIdx.x << 5) + (pair << 4);

    // zero h LDS (2048 dwords)
    for (int i = tid; i < 2048; i += 512) (&hx[0][0][0][0][0][0])[i] = 0;

    // transposed weight A-frags: row = unit u = 16T+l15, k = 16c+4lg+j
    h4 Wt[4], Ut[4];
#pragma unroll
    for (int c = 0; c < 4; ++c) {
        const int u = 16 * T + l15;
#pragma unroll
        for (int j = 0; j < 4; ++j) {
            Wt[c][j] = (_Float16)W[(16 * c + 4 * lg + j) * H + u];
            Ut[c][j] = (_Float16)U[(16 * c + 4 * lg + j) * H + u];
        }
    }
    float bgp[4], Ku[4];
#pragma unroll
    for (int r = 0; r < 4; ++r) {
        int u = 16 * T + 4 * lg + r;
        float g = bg[u], q = bu[u];
        bgp[r] = -LOG2E * g;
        Ku[r]  = exp2f(2.f * LOG2E * (g - q));
    }

    const float zs  = sigm(zeta[0]);
    const float ns  = sigm(nu[0]);
    const float zns = zs + ns;

    float hc[4] = {0.f, 0.f, 0.f, 0.f};

    // x B-frags from f16 rows: col = batch (batchbase+l15), k-chunk c: units 16c+4lg..+3
#define XADDR(t, c) (&last0[((size_t)(t) * BATCH + batchbase + l15) * H + 16 * (c) + 4 * lg])
    uint2 xc[4], xn[4], xp[4];
#pragma unroll
    for (int c = 0; c < 4; ++c) {
        xc[c] = *reinterpret_cast<const uint2*>(XADDR(0, c));
        xn[c] = *reinterpret_cast<const uint2*>(XADDR(1, c));
    }

    __syncthreads();

    int buf = 0;
#pragma unroll 1
    for (int t = 0; t < NB; ++t) {
        const int tp = (t + 2 < NB) ? (t + 2) : (NB - 1);
#pragma unroll
        for (int c = 0; c < 4; ++c)
            xp[c] = *reinterpret_cast<const uint2*>(XADDR(tp, c));

        HB hf[4];
#pragma unroll
        for (int c = 0; c < 4; ++c) {
            uint2 v = *reinterpret_cast<const uint2*>(&hx[buf][pair][c][lg][l15][0]);
            hf[c].u[0] = v.x; hf[c].u[1] = v.y;
        }

        f32x4 ax = {0.f, 0.f, 0.f, 0.f};
        f32x4 ah = {0.f, 0.f, 0.f, 0.f};
#pragma unroll
        for (int c = 0; c < 4; ++c) {
            HB xv; xv.u[0] = xc[c].x; xv.u[1] = xc[c].y;
            ax = __builtin_amdgcn_mfma_f32_16x16x16f16(Wt[c], xv.v, ax, 0, 0, 0);
        }
#pragma unroll
        for (int c = 0; c < 4; ++c)
            ah = __builtin_amdgcn_mfma_f32_16x16x16f16(Ut[c], hf[c].v, ah, 0, 0, 0);

        HB ho;
#pragma unroll
        for (int r = 0; r < 4; ++r)
            act_update(ax[r] + ah[r], bgp[r], Ku[r], zs, zns, hc[r]);
        ho.h[0] = __builtin_amdgcn_cvt_pkrtz(hc[0], hc[1]);
        ho.h[1] = __builtin_amdgcn_cvt_pkrtz(hc[2], hc[3]);

        *reinterpret_cast<uint2*>(&hx[buf ^ 1][pair][T][lg][l15][0]) = make_uint2(ho.u[0], ho.u[1]);
        lds_barrier();                 // ds drained; global prefetch in flight
        buf ^= 1;
#pragma unroll
        for (int c = 0; c < 4; ++c) { xc[c] = xn[c]; xn[c] = xp[c]; }
    }
#undef XADDR

    // stage final h (C layout: row = unit 16T+4lg+r, col = batch l15)
#pragma unroll
    for (int r = 0; r < 4; ++r) hsf[pair][l15][16 * T + 4 * lg + r] = hc[r];
    __syncthreads();

    for (int p = tid; p < 2 * 16 * OUTD; p += 512) {
        int pr = p / (16 * OUTD);
        int q  = p - pr * (16 * OUTD);
        int s  = q / OUTD;
        int o  = q - s * OUTD;
        float a = Bout[o];
#pragma unroll
        for (int u = 0; u < H; ++u) a = fmaf(hsf[pr][s][u], Wout[u * OUTD + o], a);
        out[(size_t)((blockIdx.x << 5) + (pr << 4) + s) * OUTD + o] = a;
    }
}

extern "C" void kernel_launch(void* const* d_in, const int* in_sizes, int n_in,
                              void* d_out, int out_size, void* d_ws, size_t ws_size,
                              hipStream_t stream) {
    const float* x    = (const float*)d_in[0];
    const float* W0   = (const float*)d_in[2];
    const float* U0   = (const float*)d_in[3];
    const float* bg0  = (const float*)d_in[4];
    const float* bu0  = (const float*)d_in[5];
    const float* z0   = (const float*)d_in[6];
    const float* n0   = (const float*)d_in[7];
    const float* W1   = (const float*)d_in[8];
    const float* U1   = (const float*)d_in[9];
    const float* bg1  = (const float*)d_in[10];
    const float* bu1  = (const float*)d_in[11];
    const float* z1   = (const float*)d_in[12];
    const float* n1   = (const float*)d_in[13];
    const float* Wout = (const float*)d_in[14];
    const float* Bout = (const float*)d_in[15];
    float* out = (float*)d_out;

    unsigned short* last0 = (unsigned short*)d_ws;   // 2 MB f16 scratch

    l0_kernel<<<1024, 128, 0, stream>>>(x, W0, U0, bg0, bu0, z0, n0, last0);
    l1_kernel<<<8, 512, 0, stream>>>(last0, W1, U1, bg1, bu1, z1, n1, Wout, Bout, out);
}

// Round 12
// 74.532 us; speedup vs baseline: 1.3380x; 1.3380x over previous
//
#include <hip/hip_runtime.h>
#include <hip/hip_bf16.h>

// FastGRNN 2-layer (SRNN2). T=2048, B=256, D=32, H0=H1=64, O=35, brick=32.
// Round 12: consolidation of measured-best components.
// l0 = round-11 "duo" (35us): 1024 blocks x 128 thr (2 waves; wave w owns units
//   [32w,32w+32)); 6 bf16 K=32 MFMA + 8 act/lane per step; h via XOR-swizzled
//   bf16 LDS; ONE lgkm-only barrier/step (x prefetch stays in flight).
//   NEW: epilogue transposes h through padded fp32 LDS (stride 68 -> 2-way
//   bank aliasing = free) and stores the packed f16 layout [brick][c][lg][256].
// l1 = round-10 verbatim (23.8us): 16 blocks x 256 thr, 4-wave T-split,
//   transposed f16 K=16 MFMA, uint2 LDS h-exchange, lds_barrier, fused proj.

#define NB    64
#define BS    32
#define BATCH 256
#define D0    32
#define H     64
#define OUTD  35
#define LOG2E 1.44269504088896340736f

typedef short    bf8   __attribute__((ext_vector_type(8)));
typedef _Float16 h4    __attribute__((ext_vector_type(4)));
typedef __fp16   hf2   __attribute__((ext_vector_type(2)));
typedef float    f32x4 __attribute__((ext_vector_type(4)));

union HB { h4 v; hf2 h[2]; unsigned u[2]; };
union U4BF8 { unsigned u[4]; bf8 v; };

__device__ __forceinline__ float rcp_fast(float x) {
    return __builtin_amdgcn_rcpf(x);
}
__device__ __forceinline__ float sigm(float x) {
    return rcp_fast(1.0f + __expf(-x));
}
__device__ __forceinline__ float tanh_fast(float x) {
    float q = rcp_fast(1.0f + __expf(-2.0f * x));
    return fmaf(2.0f, q, -1.0f);
}
__device__ __forceinline__ short f2bf(float f) {
    __hip_bfloat16 b = __float2bfloat16(f);
    return __builtin_bit_cast(short, b);
}
__device__ __forceinline__ unsigned pk2bf(float lo, float hi) {
    __hip_bfloat162 h2 = __float22bfloat162_rn(make_float2(lo, hi));
    unsigned r;
    __builtin_memcpy(&r, &h2, 4);
    return r;
}
__device__ __forceinline__ unsigned pk2f16(float lo, float hi) {
    hf2 h2 = __builtin_amdgcn_cvt_pkrtz(lo, hi);
    unsigned r;
    __builtin_memcpy(&r, &h2, 4);
    return r;
}
// LDS-only barrier: drains ds ops, leaves global loads in flight
__device__ __forceinline__ void lds_barrier() {
    asm volatile("s_waitcnt lgkmcnt(0)\n\ts_barrier" ::: "memory");
}
// byte swizzle within a 128-B h row (16-aligned: b128 reads stay aligned)
__device__ __forceinline__ int swz_x(int s) {
    return ((s & 7) << 4) ^ ((s & 8) << 2);
}
// 2-transcendental fused activation
__device__ __forceinline__ void act_update(float pre, float bgp, float Ku,
                                           float zs, float zns, float& hcr) {
    float t  = fminf(fmaxf(pre, -12.f), 12.f);
    float a  = exp2f(fmaf(t, -LOG2E, bgp));
    float b  = a * a * Ku;
    float da = 1.f + a, db = 1.f + b;
    float rr = rcp_fast(da * db);
    float z  = rr * db;
    float ib = rr * da;
    float c  = fmaf(2.f, ib, -1.f);
    float w  = fmaf(-zs, z, zns);
    hcr = fmaf(z, hcr, w * c);
}

// --------- Layer 0 duo: 1024 blocks x 128 thr; wave w owns 32 units ---------
__global__ __launch_bounds__(128, 2) void l0_kernel(
    const float* __restrict__ x,      // [2048][256][32]
    const float* __restrict__ W,      // [32][64]
    const float* __restrict__ U,      // [64][64]
    const float* __restrict__ bg,
    const float* __restrict__ bu,
    const float* __restrict__ zeta,
    const float* __restrict__ nu,
    unsigned* __restrict__ last0pk)   // packed f16: [64][4][4][256] uint2
{
    __shared__ unsigned char hb[2][16 * 128];   // bf16 h, swizzled rows (4 KB)
    __shared__ float hq[16][68];                // fp32 transpose pad (+4) 4.25KB

    const int tid  = threadIdx.x;
    const int lane = tid & 63;
    const int w    = __builtin_amdgcn_readfirstlane(tid >> 6);   // 0..1
    const int l15  = lane & 15;
    const int lg   = lane >> 4;

    const int brick     = blockIdx.x >> 4;
    const int batchbase = (blockIdx.x & 15) << 4;

    // zero hb[0]: 2 KB / 128 thr = 16 B each
    *reinterpret_cast<float4*>(&hb[0][tid * 16]) = make_float4(0.f, 0.f, 0.f, 0.f);

    // weight B-frags (normal orientation): col = uc, k = 8lg+j
    bf8 Wb[2], Ub0[2], Ub1[2];
    float bgc[2], buc[2];
#pragma unroll
    for (int T = 0; T < 2; ++T) {
        const int uc = 32 * w + 16 * T + l15;
#pragma unroll
        for (int j = 0; j < 8; ++j) {
            Wb[T][j]  = f2bf(W[(8 * lg + j) * H + uc]);
            Ub0[T][j] = f2bf(U[(8 * lg + j) * H + uc]);
            Ub1[T][j] = f2bf(U[(32 + 8 * lg + j) * H + uc]);
        }
        bgc[T] = bg[uc];
        buc[T] = bu[uc];
    }

    const float zs  = sigm(zeta[0]);
    const float ns  = sigm(nu[0]);
    const float zns = zs + ns;

    float hc[2][4];
#pragma unroll
    for (int T = 0; T < 2; ++T)
#pragma unroll
        for (int r = 0; r < 4; ++r) hc[T][r] = 0.f;

    const float* xbase = x + ((size_t)(brick * BS) * BATCH + batchbase + l15) * D0 + 8 * lg;
    const size_t xstep = (size_t)BATCH * D0;

    float4 xa0 = reinterpret_cast<const float4*>(xbase)[0];
    float4 xa1 = reinterpret_cast<const float4*>(xbase)[1];
    float4 xn0 = reinterpret_cast<const float4*>(xbase + xstep)[0];
    float4 xn1 = reinterpret_cast<const float4*>(xbase + xstep)[1];

    int woff[2][4];
#pragma unroll
    for (int T = 0; T < 2; ++T)
#pragma unroll
        for (int r = 0; r < 4; ++r) {
            int s = 4 * lg + r;
            woff[T][r] = s * 128 + (((32 * w + 16 * T + l15) * 2) ^ swz_x(s));
        }
    const int rswz = swz_x(l15);

    __syncthreads();

    int cur = 0;
#pragma unroll 1
    for (int t = 0; t < BS; ++t) {
        const int tp = (t + 2 < BS) ? (t + 2) : (BS - 1);
        float4 p0 = reinterpret_cast<const float4*>(xbase + (size_t)tp * xstep)[0];
        float4 p1 = reinterpret_cast<const float4*>(xbase + (size_t)tp * xstep)[1];

        U4BF8 xp;
        xp.u[0] = pk2bf(xa0.x, xa0.y);
        xp.u[1] = pk2bf(xa0.z, xa0.w);
        xp.u[2] = pk2bf(xa1.x, xa1.y);
        xp.u[3] = pk2bf(xa1.z, xa1.w);

        // h A-frags (row l15), swizzled conflict-free b128
        const unsigned char* hr = &hb[cur][l15 * 128];
        bf8 ha0 = *reinterpret_cast<const bf8*>(hr + ((16 * lg) ^ rswz));
        bf8 ha1 = *reinterpret_cast<const bf8*>(hr + ((64 + 16 * lg) ^ rswz));

        unsigned char* wb = &hb[cur ^ 1][0];
#pragma unroll
        for (int T = 0; T < 2; ++T) {
            f32x4 a = {0.f, 0.f, 0.f, 0.f};
            a = __builtin_amdgcn_mfma_f32_16x16x32_bf16(xp.v, Wb[T], a, 0, 0, 0);
            a = __builtin_amdgcn_mfma_f32_16x16x32_bf16(ha0, Ub0[T], a, 0, 0, 0);
            a = __builtin_amdgcn_mfma_f32_16x16x32_bf16(ha1, Ub1[T], a, 0, 0, 0);

#pragma unroll
            for (int r = 0; r < 4; ++r) {
                float z = sigm(a[r] + bgc[T]);
                float c = tanh_fast(a[r] + buc[T]);
                float wq = fmaf(-zs, z, zns);
                hc[T][r] = fmaf(z, hc[T][r], wq * c);
            }
            unsigned pkA = pk2bf(hc[T][0], hc[T][1]);
            unsigned pkB = pk2bf(hc[T][2], hc[T][3]);
            *reinterpret_cast<unsigned short*>(wb + woff[T][0]) = (unsigned short)pkA;
            *reinterpret_cast<unsigned short*>(wb + woff[T][1]) = (unsigned short)(pkA >> 16);
            *reinterpret_cast<unsigned short*>(wb + woff[T][2]) = (unsigned short)pkB;
            *reinterpret_cast<unsigned short*>(wb + woff[T][3]) = (unsigned short)(pkB >> 16);
        }
        lds_barrier();     // ds drained; x prefetch stays in flight
        cur ^= 1;
        xa0 = xn0; xa1 = xn1;
        xn0 = p0;  xn1 = p1;
    }

    // ---- epilogue: transpose to packed f16 layout [brick][c][lg][256] ----
    // write fp32 h to padded LDS: hq[seq][unit]
#pragma unroll
    for (int T = 0; T < 2; ++T)
#pragma unroll
        for (int r = 0; r < 4; ++r)
            hq[4 * lg + r][32 * w + 16 * T + l15] = hc[T][r];
    __syncthreads();

    // lane (l15=batch-in-tile, lg): chunk c -> units 16c+4lg..+3 of seq l15
#pragma unroll
    for (int c = 0; c < 4; ++c) {
        float4 v = *reinterpret_cast<const float4*>(&hq[l15][16 * c + 4 * lg]);
        uint2 o = make_uint2(pk2f16(v.x, v.y), pk2f16(v.z, v.w));
        size_t idx = ((((size_t)brick * 4 + c) * 4 + lg) * 256 + batchbase + l15) * 2;
        *reinterpret_cast<uint2*>(&last0pk[idx]) = o;
    }
}

// ------- Layer 1 (round-10 verbatim): 16 blocks x 256, 4-wave T-split -------
__global__ __launch_bounds__(256, 2) void l1_kernel(
    const unsigned* __restrict__ last0pk,  // [64][4][4][256] uint2
    const float* __restrict__ W,           // [64][64]
    const float* __restrict__ U,           // [64][64]
    const float* __restrict__ bg,
    const float* __restrict__ bu,
    const float* __restrict__ zeta,
    const float* __restrict__ nu,
    const float* __restrict__ Wout,        // [64][35]
    const float* __restrict__ Bout,        // [35]
    float* __restrict__ out)               // [256][35]
{
    __shared__ unsigned hx[2][4][4][16][2];   // [buf][chunk][lg][s][dword] 4KB
    __shared__ float hsf[16][H];

    const int tid  = threadIdx.x;
    const int lane = tid & 63;
    const int T    = __builtin_amdgcn_readfirstlane(tid >> 6);   // unit tile
    const int l15  = lane & 15;
    const int lg   = lane >> 4;

    const int batchbase = blockIdx.x << 4;

    for (int i = tid; i < 1024; i += 256) (&hx[0][0][0][0][0])[i] = 0;

    h4 Wt[4], Ut[4];
#pragma unroll
    for (int c = 0; c < 4; ++c) {
        const int u = 16 * T + l15;
#pragma unroll
        for (int j = 0; j < 4; ++j) {
            Wt[c][j] = (_Float16)W[(16 * c + 4 * lg + j) * H + u];
            Ut[c][j] = (_Float16)U[(16 * c + 4 * lg + j) * H + u];
        }
    }
    float bgp[4], Ku[4];
#pragma unroll
    for (int r = 0; r < 4; ++r) {
        int u = 16 * T + 4 * lg + r;
        float g = bg[u], q = bu[u];
        bgp[r] = -LOG2E * g;
        Ku[r]  = exp2f(2.f * LOG2E * (g - q));
    }

    const float zs  = sigm(zeta[0]);
    const float ns  = sigm(nu[0]);
    const float zns = zs + ns;

    float hc[4] = {0.f, 0.f, 0.f, 0.f};

#define XIDX(t, c) (((((size_t)(t) * 4 + (c)) * 4 + lg) * 256 + batchbase + l15) * 2)
    uint2 xc[4], xn[4], xp[4];
#pragma unroll
    for (int c = 0; c < 4; ++c) {
        xc[c] = *reinterpret_cast<const uint2*>(&last0pk[XIDX(0, c)]);
        xn[c] = *reinterpret_cast<const uint2*>(&last0pk[XIDX(1, c)]);
    }

    __syncthreads();

    int buf = 0;
#pragma unroll 1
    for (int t = 0; t < NB; ++t) {
        const int tp = (t + 2 < NB) ? (t + 2) : (NB - 1);
#pragma unroll
        for (int c = 0; c < 4; ++c)
            xp[c] = *reinterpret_cast<const uint2*>(&last0pk[XIDX(tp, c)]);

        HB hf[4];
#pragma unroll
        for (int c = 0; c < 4; ++c) {
            uint2 v = *reinterpret_cast<const uint2*>(&hx[buf][c][lg][l15][0]);
            hf[c].u[0] = v.x; hf[c].u[1] = v.y;
        }

        f32x4 ax = {0.f, 0.f, 0.f, 0.f};
        f32x4 ah = {0.f, 0.f, 0.f, 0.f};
#pragma unroll
        for (int c = 0; c < 4; ++c) {
            HB xv; xv.u[0] = xc[c].x; xv.u[1] = xc[c].y;
            ax = __builtin_amdgcn_mfma_f32_16x16x16f16(Wt[c], xv.v, ax, 0, 0, 0);
        }
#pragma unroll
        for (int c = 0; c < 4; ++c)
            ah = __builtin_amdgcn_mfma_f32_16x16x16f16(Ut[c], hf[c].v, ah, 0, 0, 0);

        HB ho;
#pragma unroll
        for (int r = 0; r < 4; ++r)
            act_update(ax[r] + ah[r], bgp[r], Ku[r], zs, zns, hc[r]);
        ho.h[0] = __builtin_amdgcn_cvt_pkrtz(hc[0], hc[1]);
        ho.h[1] = __builtin_amdgcn_cvt_pkrtz(hc[2], hc[3]);

        *reinterpret_cast<uint2*>(&hx[buf ^ 1][T][lg][l15][0]) = make_uint2(ho.u[0], ho.u[1]);
        lds_barrier();                 // ds drained; global prefetch in flight
        buf ^= 1;
#pragma unroll
        for (int c = 0; c < 4; ++c) { xc[c] = xn[c]; xn[c] = xp[c]; }
    }
#undef XIDX

#pragma unroll
    for (int r = 0; r < 4; ++r) hsf[l15][16 * T + 4 * lg + r] = hc[r];
    __syncthreads();

    for (int p = tid; p < 16 * OUTD; p += 256) {
        int s = p / OUTD;
        int o = p - s * OUTD;
        float a = Bout[o];
#pragma unroll
        for (int u = 0; u < H; ++u) a = fmaf(hsf[s][u], Wout[u * OUTD + o], a);
        out[(size_t)(batchbase + s) * OUTD + o] = a;
    }
}

extern "C" void kernel_launch(void* const* d_in, const int* in_sizes, int n_in,
                              void* d_out, int out_size, void* d_ws, size_t ws_size,
                              hipStream_t stream) {
    const float* x    = (const float*)d_in[0];
    const float* W0   = (const float*)d_in[2];
    const float* U0   = (const float*)d_in[3];
    const float* bg0  = (const float*)d_in[4];
    const float* bu0  = (const float*)d_in[5];
    const float* z0   = (const float*)d_in[6];
    const float* n0   = (const float*)d_in[7];
    const float* W1   = (const float*)d_in[8];
    const float* U1   = (const float*)d_in[9];
    const float* bg1  = (const float*)d_in[10];
    const float* bu1  = (const float*)d_in[11];
    const float* z1   = (const float*)d_in[12];
    const float* n1   = (const float*)d_in[13];
    const float* Wout = (const float*)d_in[14];
    const float* Bout = (const float*)d_in[15];
    float* out = (float*)d_out;

    unsigned* last0pk = (unsigned*)d_ws;   // 2 MB packed-f16 scratch

    l0_kernel<<<1024, 128, 0, stream>>>(x, W0, U0, bg0, bu0, z0, n0, last0pk);
    l1_kernel<<<16, 256, 0, stream>>>(last0pk, W1, U1, bg1, bu1, z1, n1, Wout, Bout, out);
}